// Round 8
// baseline (149.046 us; speedup 1.0000x reference)
//
#include <hip/hip_runtime.h>

// C51 distributional projection — zero-atomic scan, barrier-free 1-wave
// pipeline, split LDS in/out buffers, spill-free register staging.
//
// Evidence trail:
//  R2: 2 LDS atomics/elem -> 287 us (cost tracked atomic count). R3/R4:
//  zero-atomic sliding scan -> 54 us. R5: in-place scan read/write overtake
//  -> FAIL. R6: stage[52]+d[51] live across scan -> scratch spill (WRITE
//  104->209 MB) + __syncthreads drained the prefetch -> 112 us. R7: split
//  bufIn/bufOut + barrier-free fixed the structure, but __launch_bounds__(64)
//  let the allocator target high occupancy -> capped at 88 VGPR -> stage[]
//  STILL spilled (WRITE 195 MB, FETCH 98 MB) -> 148 us.
//
// Fix here: __launch_bounds__(64, 1). Occupancy is LDS-capped at 6 wg/CU
// (26 KB/wg) = 1.5 waves/SIMD no matter what the allocator does, so granting
// it a 1-wave budget (>=340 VGPRs) costs nothing and removes the spill. The
// reg-staged prefetch then gives the compiler PRECISE counted vmcnt waits
// (register deps), so slab k+1's 13 global_load_dwordx4 stay in flight
// across slab k's ~1000-cycle scan: per-CU in-flight ~ 6 wg x 13 KB x ~60%
// duty ~ 47 KB > 25 KB BW-delay product -> HBM-saturable.
//
// Pipeline per slab k (1-wave wg, no barriers — all ordering is intra-wave;
// per-wave DS ops execute in order, VMEM deps via counted vmcnt):
//   ds_write stage regs -> bufIn   (waits slab k's loads only)
//   issue slab k+1's 13 loads      (fly during scan)
//   scan bufIn -> bufOut           (reads inside loop; no aliasing)
//   float4 store bufOut -> global
//
// Scan math (unchanged since R3, absmax 3.9e-3): b_j = clip(2.5r + 25 +
// 0.99*beta*z_j*2.5, 0, 50) is monotone in j with step 0.99 < 1; after the
// integer-bin adjust upper == lower+1, so scatter targets advance 0/1 per
// atom and a sliding 2-register accumulator emits each bin exactly once.

namespace {

constexpr int NA    = 51;
constexpr int BLOCK = 64;            // one wave; lanes == rows per slab
constexpr int ROWS  = 64;
constexpr int NSLAB = 4;             // slabs per workgroup
constexpr int ELEMS = ROWS * NA;     // 3264 floats = 13,056 B per buffer
constexpr int VECS  = ELEMS / 4;     // 816 float4s
constexpr int VPL   = 13;            // float4s per lane (last iter: tid<48)

__device__ __forceinline__ void scan_row(float r, float g, int rb,
                                         const float* __restrict__ in,
                                         float* __restrict__ ob)
{
    int   cur  = 0;
    float accL = 0.0f, accU = 0.0f;

    #pragma unroll
    for (int j = 0; j < NA; ++j) {
        const float d = in[rb + j];                    // ds_read_b32, 2-way = free
        const float z = fmaf((float)j, 0.4f, -10.0f);  // support atom z_j
        float t = fmaf(g, z, r);                       // r + 0.99*beta*z_j
        t = fminf(fmaxf(t, -10.0f), 10.0f);
        const float b = (t + 10.0f) * 2.5f;            // in [0, 50]

        const float lf = floorf(b);
        int lower = (int)lf;
        if (b == lf && lower > 0) lower -= 1;          // integer-bin adjust
        // invariant: upper == lower + 1, lower in [0,49]

        const float wl = d * ((float)(lower + 1) - b);
        const float wu = d * (b - (float)lower);

        while (cur < lower) {                          // emit finalized bins
            ob[rb + cur] = accL;
            accL = accU; accU = 0.0f; ++cur;
        }
        accL += wl;
        accU += wu;
    }
    ob[rb + cur]     = accL;
    ob[rb + cur + 1] = accU;                           // cur+1 <= 50
    for (int k = cur + 2; k < NA; ++k) ob[rb + k] = 0.0f;
}

__global__ __launch_bounds__(BLOCK, 1)   // 1 wave/EU min: LDS caps occupancy
void c51_project(const float* __restrict__ next_dist,  // anyway; big VGPR
                 const float* __restrict__ rewards,    // budget -> NO SPILL
                 const float* __restrict__ bootstrap,
                 float* __restrict__ out,
                 int B)
{
    __shared__ __align__(16) float bufIn[ELEMS];
    __shared__ __align__(16) float bufOut[ELEMS];

    const int tid = threadIdx.x;
    const long long wg_row0 = (long long)blockIdx.x * (ROWS * NSLAB);

    if ((wg_row0 + ROWS * NSLAB) <= (long long)B) {
        // ---- fast path: barrier-free software pipeline over 4 slabs ----
        float r[NSLAB], g[NSLAB];
        #pragma unroll
        for (int k = 0; k < NSLAB; ++k) {
            const long long row = wg_row0 + (long long)k * ROWS + tid;
            r[k] = rewards[row];
            g[k] = bootstrap[row] * 0.99f;
        }

        // prologue: issue slab 0's loads
        float4 stage[VPL];
        {
            const float4* __restrict__ in4 =
                (const float4*)(next_dist + wg_row0 * NA);
            #pragma unroll
            for (int i = 0; i < VPL; ++i) {
                const int v = tid + i * BLOCK;
                if (v < VECS) stage[i] = in4[v];
            }
        }

        #pragma unroll
        for (int k = 0; k < NSLAB; ++k) {
            // stage slab k into bufIn — compiler emits COUNTED vmcnt waits
            // on the stage-register deps (slab k's loads only).
            {
                float4* l4 = (float4*)bufIn;
                #pragma unroll
                for (int i = 0; i < VPL; ++i) {
                    const int v = tid + i * BLOCK;
                    if (v < VECS) l4[v] = stage[i];
                }
            }
            // issue slab k+1's loads NOW — in flight across the scan.
            if (k + 1 < NSLAB) {
                const float4* __restrict__ n4 =
                    (const float4*)(next_dist + (wg_row0 + (long long)(k + 1) * ROWS) * NA);
                #pragma unroll
                for (int i = 0; i < VPL; ++i) {
                    const int v = tid + i * BLOCK;
                    if (v < VECS) stage[i] = n4[v];
                }
            }

            // scan: bufIn -> bufOut (no aliasing; per-wave DS ops in order)
            scan_row(r[k], g[k], tid * NA, bufIn, bufOut);

            // coalesced store of slab k
            {
                float4* __restrict__ o4 =
                    (float4*)(out + (wg_row0 + (long long)k * ROWS) * NA);
                const float4* __restrict__ s4 = (const float4*)bufOut;
                #pragma unroll
                for (int i = 0; i < VPL; ++i) {
                    const int v = tid + i * BLOCK;
                    if (v < VECS) o4[v] = s4[v];
                }
            }
        }
    } else {
        // ---- tail path (last workgroup only): guarded, unpipelined ----
        for (int k = 0; k < NSLAB; ++k) {
            const long long base_row = wg_row0 + (long long)k * ROWS;
            const int rows_here = (int)min((long long)ROWS, (long long)B - base_row);
            if (rows_here <= 0) break;
            const int elems_here = rows_here * NA;
            const long long base_elem = base_row * NA;

            float r = 0.0f, g = 0.0f;
            if (tid < rows_here) {
                r = rewards[base_row + tid];
                g = bootstrap[base_row + tid] * 0.99f;
            }
            for (int e = tid; e < elems_here; e += BLOCK)
                bufIn[e] = next_dist[base_elem + e];
            __syncthreads();
            if (tid < rows_here) scan_row(r, g, tid * NA, bufIn, bufOut);
            __syncthreads();
            for (int e = tid; e < elems_here; e += BLOCK)
                out[base_elem + e] = bufOut[e];
            __syncthreads();
        }
    }
}

} // namespace

extern "C" void kernel_launch(void* const* d_in, const int* in_sizes, int n_in,
                              void* d_out, int out_size, void* d_ws, size_t ws_size,
                              hipStream_t stream)
{
    const float* next_dist = (const float*)d_in[0];
    const float* rewards   = (const float*)d_in[1];
    const float* bootstrap = (const float*)d_in[2];
    float* out = (float*)d_out;

    const int B = in_sizes[1];                          // rewards element count
    const int rows_per_wg = ROWS * NSLAB;               // 256
    const int nblocks = (B + rows_per_wg - 1) / rows_per_wg;  // 2048 for B=524288

    c51_project<<<dim3(nblocks), dim3(BLOCK), 0, stream>>>(
        next_dist, rewards, bootstrap, out, B);
}

// Round 9
// 100.417 us; speedup vs baseline: 1.4843x; 1.4843x over previous
//
#include <hip/hip_runtime.h>

// C51 distributional projection — zero-atomic scan + async global->LDS DMA
// pipeline with hand-counted vmcnt (T3/T4), barrier-free 1-wave workgroups.
//
// Evidence trail:
//  R2: LDS atomics -> 287 us (cost ~ atomic count). R3/R4: zero-atomic
//  sliding scan -> 54 us (VALU 33%, HBM 48%, nothing saturated; per-wave
//  load-issue duty ~25% is the limiter). R5: in-place scan overtake -> FAIL.
//  R6/R7/R8: reg-staged prefetch (stage[52]) spilled to scratch no matter
//  what (WRITE 104->195 MB, FETCH 54->98 MB); __launch_bounds__ didn't move
//  the allocator (VGPR_Count pinned at 88). Conclusion: stop staging through
//  registers.
//
// This version stages via __builtin_amdgcn_global_load_lds (16 B/lane DMA,
// no VGPR round-trip, async under vmcnt):
//   - input double-buffer bufA/bufB (13,312 B each incl. 256 B pad for the
//     13th chunk's 16 tail lanes; their global srcs are clamped in-slab and
//     their data lands in the pad, never read), scan output bufOut (13,056 B).
//     39.7 KB LDS -> 4 wg/CU; 4 x 13 KB DMA in flight > 25 KB BDP.
//   - NO barriers, NO vmcnt(0): 1-wave wg. Hand-counted waits, statically
//     derived from the fixed VMEM issue order (13 ops per prefetch/store):
//       L0 L1 [w13] scan0 S0 L2 [w26] scan1 S1 L3 [w26] scan2 S2 [w13] scan3 S3
//     each wait leaves exactly the younger ops outstanding, so the scanned
//     slab's 13 DMAs are retired (vmcnt retires oldest-first).
//   - DS ops are in-order per wave: scan k's bufOut writes never pass
//     S(k-1)'s bufOut reads; prefetch into a buffer is issued only after the
//     scan that read it has fully consumed its loads.
//
// Scan math (unchanged since R3, absmax 3.9e-3): b_j = clip(2.5r + 25 +
// 2.475*beta*z_j, 0, 50) is monotone in j with step 0.99 < 1; after the
// integer-bin adjust upper == lower+1, so scatter targets advance 0/1 per
// atom and a sliding 2-register accumulator emits each bin exactly once.

namespace {

constexpr int NA     = 51;
constexpr int BLOCK  = 64;             // one wave; lanes == rows per slab
constexpr int ROWS   = 64;
constexpr int NSLAB  = 4;              // slabs per workgroup
constexpr int ELEMS  = ROWS * NA;      // 3264 floats = 13,056 B
constexpr int VECS   = ELEMS / 4;      // 816 float4s
constexpr int CHUNKS = 13;             // ceil(816/64)
constexpr int BUFSZ  = ELEMS + 64;     // +64-float pad absorbs chunk-12 tail

template <int N>
__device__ __forceinline__ void vwait() {
    asm volatile("s_waitcnt vmcnt(%0)" :: "i"(N) : "memory");
}

// Async DMA: one 16 B chunk per lane, LDS dest = uniform base + lane*16.
__device__ __forceinline__ void dma16(const float4* gsrc, float* ldst_uniform) {
    __builtin_amdgcn_global_load_lds(
        (const __attribute__((address_space(1))) void*)gsrc,
        (__attribute__((address_space(3))) void*)ldst_uniform,
        16, 0, 0);
}

// Issue 13 DMA chunks for one slab (13 vmcnt ops, no VGPR staging).
__device__ __forceinline__ void prefetch_slab(const float* __restrict__ gbase,
                                              float* lbuf, int tid) {
    const float4* g4 = (const float4*)gbase;
    #pragma unroll
    for (int i = 0; i < CHUNKS; ++i) {
        const int v = tid + i * BLOCK;
        const float4* src = g4 + ((v < VECS) ? v : tid);  // clamp OOB -> pad
        dma16(src, lbuf + i * (BLOCK * 4));               // uniform LDS base
    }
}

// Coalesced float4 store of one slab (13 vmcnt ops).
__device__ __forceinline__ void store_slab(float* __restrict__ gbase,
                                           const float* lbuf, int tid) {
    float4* o4 = (float4*)gbase;
    const float4* s4 = (const float4*)lbuf;
    #pragma unroll
    for (int i = 0; i < CHUNKS; ++i) {
        const int v = tid + i * BLOCK;
        if (v < VECS) o4[v] = s4[v];   // chunk 12: 48 lanes, still 1 instr
    }
}

__device__ __forceinline__ void scan_row(float r, float g, int rb,
                                         const float* __restrict__ in,
                                         float* __restrict__ ob)
{
    int   cur  = 0;
    float accL = 0.0f, accU = 0.0f;

    #pragma unroll
    for (int j = 0; j < NA; ++j) {
        const float d = in[rb + j];                    // ds_read, 2-way = free
        const float z = fmaf((float)j, 0.4f, -10.0f);  // support atom z_j
        float t = fmaf(g, z, r);                       // r + 0.99*beta*z_j
        t = fminf(fmaxf(t, -10.0f), 10.0f);
        const float b = (t + 10.0f) * 2.5f;            // in [0, 50]

        const float lf = floorf(b);
        int lower = (int)lf;
        if (b == lf && lower > 0) lower -= 1;          // integer-bin adjust
        // invariant: upper == lower + 1, lower in [0,49]

        const float wl = d * ((float)(lower + 1) - b);
        const float wu = d * (b - (float)lower);

        while (cur < lower) {                          // emit finalized bins
            ob[rb + cur] = accL;
            accL = accU; accU = 0.0f; ++cur;
        }
        accL += wl;
        accU += wu;
    }
    ob[rb + cur]     = accL;
    ob[rb + cur + 1] = accU;                           // cur+1 <= 50
    for (int k = cur + 2; k < NA; ++k) ob[rb + k] = 0.0f;
}

__global__ __launch_bounds__(BLOCK)
void c51_project(const float* __restrict__ next_dist,
                 const float* __restrict__ rewards,
                 const float* __restrict__ bootstrap,
                 float* __restrict__ out,
                 int B)
{
    __shared__ __align__(16) float bufA[BUFSZ];
    __shared__ __align__(16) float bufB[BUFSZ];
    __shared__ __align__(16) float bufOut[ELEMS];

    const int tid = threadIdx.x;
    const long long wg_row0 = (long long)blockIdx.x * (ROWS * NSLAB);

    if ((wg_row0 + ROWS * NSLAB) <= (long long)B) {
        // ---- fast path: barrier-free DMA pipeline over 4 slabs ----
        float r[NSLAB], g[NSLAB];
        #pragma unroll
        for (int k = 0; k < NSLAB; ++k) {
            const long long row = wg_row0 + (long long)k * ROWS + tid;
            r[k] = rewards[row];                    // oldest VMEM ops: retired
            g[k] = bootstrap[row] * 0.99f;          // by the first vwait<13>
        }

        const float* in0 = next_dist + wg_row0 * NA;
        float*       ou0 = out       + wg_row0 * NA;

        // prologue: slabs 0 and 1 in flight
        prefetch_slab(in0,             bufA, tid);   // L0
        prefetch_slab(in0 + 1 * ELEMS, bufB, tid);   // L1

        // iter 0: wait L0 (younger: L1 = 13)
        vwait<13>();
        scan_row(r[0], g[0], tid * NA, bufA, bufOut);
        store_slab(ou0,             bufOut, tid);    // S0
        prefetch_slab(in0 + 2 * ELEMS, bufA, tid);   // L2 (scan0 done reading)

        // iter 1: wait L1 (younger: S0 + L2 = 26)
        vwait<26>();
        scan_row(r[1], g[1], tid * NA, bufB, bufOut);
        store_slab(ou0 + 1 * ELEMS, bufOut, tid);    // S1
        prefetch_slab(in0 + 3 * ELEMS, bufB, tid);   // L3

        // iter 2: wait L2 (younger: S1 + L3 = 26)
        vwait<26>();
        scan_row(r[2], g[2], tid * NA, bufA, bufOut);
        store_slab(ou0 + 2 * ELEMS, bufOut, tid);    // S2

        // iter 3: wait L3 (younger: S2 = 13)
        vwait<13>();
        scan_row(r[3], g[3], tid * NA, bufB, bufOut);
        store_slab(ou0 + 3 * ELEMS, bufOut, tid);    // S3
    } else {
        // ---- tail path (last workgroup only): plain, unpipelined ----
        for (int k = 0; k < NSLAB; ++k) {
            const long long base_row = wg_row0 + (long long)k * ROWS;
            const int rows_here = (int)min((long long)ROWS, (long long)B - base_row);
            if (rows_here <= 0) break;
            const int elems_here = rows_here * NA;
            const long long base_elem = base_row * NA;

            float r = 0.0f, g = 0.0f;
            if (tid < rows_here) {
                r = rewards[base_row + tid];
                g = bootstrap[base_row + tid] * 0.99f;
            }
            for (int e = tid; e < elems_here; e += BLOCK)
                bufA[e] = next_dist[base_elem + e];
            __syncthreads();
            if (tid < rows_here) scan_row(r, g, tid * NA, bufA, bufOut);
            __syncthreads();
            for (int e = tid; e < elems_here; e += BLOCK)
                out[base_elem + e] = bufOut[e];
            __syncthreads();
        }
    }
}

} // namespace

extern "C" void kernel_launch(void* const* d_in, const int* in_sizes, int n_in,
                              void* d_out, int out_size, void* d_ws, size_t ws_size,
                              hipStream_t stream)
{
    const float* next_dist = (const float*)d_in[0];
    const float* rewards   = (const float*)d_in[1];
    const float* bootstrap = (const float*)d_in[2];
    float* out = (float*)d_out;

    const int B = in_sizes[1];                          // rewards element count
    const int rows_per_wg = ROWS * NSLAB;               // 256
    const int nblocks = (B + rows_per_wg - 1) / rows_per_wg;  // 2048 for B=524288

    c51_project<<<dim3(nblocks), dim3(BLOCK), 0, stream>>>(
        next_dist, rewards, bootstrap, out, B);
}